// Round 2
// baseline (713.675 us; speedup 1.0000x reference)
//
#include <hip/hip_runtime.h>

// Problem: B=4,S=2048 -> N=8192 tokens, D=1024, H=4096, E=4 experts, top-1 routing.
#define DN 8192
#define DD 1024
#define DH 4096
#define DE 4
#define SLOTS (DN + 512)   // padded concat token list (each expert segment 128-aligned)

typedef unsigned short u16;
typedef float f32x4 __attribute__((ext_vector_type(4)));
typedef __bf16 bf16x8 __attribute__((ext_vector_type(8)));
typedef u16 u16x2 __attribute__((ext_vector_type(2)));
typedef u16 u16x4 __attribute__((ext_vector_type(4)));

__device__ __forceinline__ u16 f2b(float f) {
  union { float f; unsigned u; } v; v.f = f;
  return (u16)((v.u + 0x7FFFu + ((v.u >> 16) & 1u)) >> 16);  // RNE f32->bf16
}

__device__ __forceinline__ void gl_lds16(const u16* g, u16* l) {
  __builtin_amdgcn_global_load_lds((const __attribute__((address_space(1))) void*)g,
                                   (__attribute__((address_space(3))) void*)l, 16, 0, 0);
}

// ---------------- router: 1 wave per token, fp64 accumulation for argmax safety ----------
__global__ __launch_bounds__(256) void router_k(const float* __restrict__ x,
    const float* __restrict__ Wr, const float* __restrict__ br,
    float* __restrict__ gval, int* __restrict__ gidx, int* __restrict__ gpos,
    int* __restrict__ counts, u16* __restrict__ xb)
{
  const int tid = blockIdx.x * 256 + threadIdx.x;
  const int n = tid >> 6, lane = tid & 63;
  const float* xr = x + (size_t)n * DD;
  double a0 = 0., a1 = 0., a2 = 0., a3 = 0.;
#pragma unroll
  for (int k = 0; k < DD / 64; ++k) {
    const int d = lane + k * 64;
    const float xv = xr[d];
    const f32x4 w = *(const f32x4*)&Wr[d * 4];
    a0 += (double)xv * w[0]; a1 += (double)xv * w[1];
    a2 += (double)xv * w[2]; a3 += (double)xv * w[3];
    xb[(size_t)n * DD + d] = f2b(xv);
  }
#pragma unroll
  for (int off = 32; off; off >>= 1) {
    a0 += __shfl_xor(a0, off);
    a1 += __shfl_xor(a1, off);
    a2 += __shfl_xor(a2, off);
    a3 += __shfl_xor(a3, off);
  }
  if (lane == 0) {
    const double l0 = a0 + br[0], l1 = a1 + br[1], l2 = a2 + br[2], l3 = a3 + br[3];
    int bi = 0; double bm = l0;
    if (l1 > bm) { bm = l1; bi = 1; }
    if (l2 > bm) { bm = l2; bi = 2; }
    if (l3 > bm) { bm = l3; bi = 3; }
    const float s = __expf((float)(l0 - bm)) + __expf((float)(l1 - bm)) +
                    __expf((float)(l2 - bm)) + __expf((float)(l3 - bm));
    gval[n] = 1.0f / s;          // max softmax prob
    gidx[n] = bi;
    gpos[n] = atomicAdd(&counts[bi], 1);
  }
}

__global__ void offsets_k(const int* __restrict__ counts, int* __restrict__ offs) {
  if (threadIdx.x == 0 && blockIdx.x == 0) {
    int o = 0;
#pragma unroll
    for (int e = 0; e < DE; ++e) { offs[e] = o; o += (counts[e] + 127) & ~127; }
    offs[DE] = o;
  }
}

__global__ __launch_bounds__(256) void scatter_k(const int* __restrict__ gidx,
    const int* __restrict__ gpos, const int* __restrict__ offs, int* __restrict__ tlist) {
  const int n = blockIdx.x * 256 + threadIdx.x;
  tlist[offs[gidx[n]] + gpos[n]] = n;
}

// ---------------- fp32 -> bf16 transpose (in: R x C, out: C x R), per blockIdx.z matrix ----
__global__ __launch_bounds__(256) void transpose_conv(const float* __restrict__ in,
    u16* __restrict__ out, int R, int C)
{
  __shared__ u16 t[64][66];
  const int r0 = blockIdx.x * 64, c0 = blockIdx.y * 64;
  const size_t mo = (size_t)blockIdx.z * R * C;
  const int tid = threadIdx.x;
  const int i = tid >> 4, j0 = (tid & 15) * 4;
#pragma unroll
  for (int k = 0; k < 4; ++k) {
    const int row = k * 16 + i;
    const f32x4 v = *(const f32x4*)&in[mo + (size_t)(r0 + row) * C + c0 + j0];
    u16x2 u01; u01[0] = f2b(v[0]); u01[1] = f2b(v[1]);
    u16x2 u23; u23[0] = f2b(v[2]); u23[1] = f2b(v[3]);
    *(u16x2*)&t[row][j0] = u01;
    *(u16x2*)&t[row][j0 + 2] = u23;
  }
  __syncthreads();
#pragma unroll
  for (int k = 0; k < 4; ++k) {
    const int p = k * 16 + i;   // out-row within tile
    u16x4 u;
    u[0] = t[j0 + 0][p]; u[1] = t[j0 + 1][p]; u[2] = t[j0 + 2][p]; u[3] = t[j0 + 3][p];
    *(u16x4*)&out[mo + (size_t)(c0 + p) * R + r0 + j0] = u;
  }
}

// ---------------- grouped GEMM1: Hb[slot,h] = silu(x[tok] @ W1[e] + b1[e]) ----------------
__global__ __launch_bounds__(256) void gemm1_k(const u16* __restrict__ xb,
    const u16* __restrict__ w1t, const float* __restrict__ b1,
    const int* __restrict__ tlist, const int* __restrict__ offs, u16* __restrict__ hb)
{
  __shared__ u16 As[4][128][8];   // [kchunk][row][8 bf16]
  __shared__ u16 Bs[4][128][8];
  const int row0 = blockIdx.x * 128;
  if (row0 >= offs[DE]) return;
  int e = 0;
  if (row0 >= offs[1]) e = 1;
  if (row0 >= offs[2]) e = 2;
  if (row0 >= offs[3]) e = 3;
  const int h0 = blockIdx.y * 128;
  const int tid = threadIdx.x;
  const int wid = tid >> 6, lane = tid & 63;

  int tA0 = tlist[row0 + lane];
  int tA1 = tlist[row0 + 64 + lane];
  if (tA0 < 0) tA0 = 0;
  if (tA1 < 0) tA1 = 0;
  const u16* pa0 = xb + (size_t)tA0 * DD + wid * 8;
  const u16* pa1 = xb + (size_t)tA1 * DD + wid * 8;
  const u16* pb0 = w1t + (size_t)e * DH * DD + (size_t)(h0 + lane) * DD + wid * 8;
  const u16* pb1 = w1t + (size_t)e * DH * DD + (size_t)(h0 + 64 + lane) * DD + wid * 8;
  u16* lA0 = &As[wid][0][0];
  u16* lA1 = &As[wid][64][0];
  u16* lB0 = &Bs[wid][0][0];
  u16* lB1 = &Bs[wid][64][0];

  const int wr = (wid >> 1) * 64, wc = (wid & 1) * 64;
  const int fr = lane & 15, fq = lane >> 4;

  f32x4 acc[4][4];
#pragma unroll
  for (int m = 0; m < 4; ++m)
#pragma unroll
    for (int n = 0; n < 4; ++n) acc[m][n] = (f32x4)(0.f);

  for (int ks = 0; ks < DD / 32; ++ks) {
    gl_lds16(pa0, lA0); gl_lds16(pa1, lA1);
    gl_lds16(pb0, lB0); gl_lds16(pb1, lB1);
    pa0 += 32; pa1 += 32; pb0 += 32; pb1 += 32;
    __syncthreads();   // compiler drains vmcnt before s_barrier
    bf16x8 af[4], bfv[4];
#pragma unroll
    for (int m = 0; m < 4; ++m) af[m] = *(const bf16x8*)&As[fq][wr + m * 16 + fr][0];
#pragma unroll
    for (int n = 0; n < 4; ++n) bfv[n] = *(const bf16x8*)&Bs[fq][wc + n * 16 + fr][0];
#pragma unroll
    for (int m = 0; m < 4; ++m)
#pragma unroll
      for (int n = 0; n < 4; ++n)
        acc[m][n] = __builtin_amdgcn_mfma_f32_16x16x32_bf16(af[m], bfv[n], acc[m][n], 0, 0, 0);
    __syncthreads();
  }

#pragma unroll
  for (int n = 0; n < 4; ++n) {
    const int h = h0 + wc + n * 16 + fr;
    const float bias = b1[(size_t)e * DH + h];
#pragma unroll
    for (int m = 0; m < 4; ++m) {
      const int r = row0 + wr + m * 16 + fq * 4;
      const f32x4 v = acc[m][n];
#pragma unroll
      for (int i = 0; i < 4; ++i) {
        const float xv = v[i] + bias;
        const float sv = xv / (1.f + __expf(-xv));   // silu
        hb[(size_t)(r + i) * DH + h] = f2b(sv);
      }
    }
  }
}

// ---------------- grouped GEMM2: out[tok,d] = (Hb[slot] @ W2[e] + b2[e]) * gate ----------
__global__ __launch_bounds__(256) void gemm2_k(const u16* __restrict__ hb,
    const u16* __restrict__ w2t, const float* __restrict__ b2,
    const int* __restrict__ tlist, const int* __restrict__ offs,
    const float* __restrict__ gval, float* __restrict__ out)
{
  __shared__ u16 As[4][128][8];
  __shared__ u16 Bs[4][128][8];
  const int row0 = blockIdx.x * 128;
  if (row0 >= offs[DE]) return;
  int e = 0;
  if (row0 >= offs[1]) e = 1;
  if (row0 >= offs[2]) e = 2;
  if (row0 >= offs[3]) e = 3;
  const int d0 = blockIdx.y * 128;
  const int tid = threadIdx.x;
  const int wid = tid >> 6, lane = tid & 63;

  const u16* pa0 = hb + (size_t)(row0 + lane) * DH + wid * 8;
  const u16* pa1 = hb + (size_t)(row0 + 64 + lane) * DH + wid * 8;
  const u16* pb0 = w2t + (size_t)e * DD * DH + (size_t)(d0 + lane) * DH + wid * 8;
  const u16* pb1 = w2t + (size_t)e * DD * DH + (size_t)(d0 + 64 + lane) * DH + wid * 8;
  u16* lA0 = &As[wid][0][0];
  u16* lA1 = &As[wid][64][0];
  u16* lB0 = &Bs[wid][0][0];
  u16* lB1 = &Bs[wid][64][0];

  const int wr = (wid >> 1) * 64, wc = (wid & 1) * 64;
  const int fr = lane & 15, fq = lane >> 4;

  f32x4 acc[4][4];
#pragma unroll
  for (int m = 0; m < 4; ++m)
#pragma unroll
    for (int n = 0; n < 4; ++n) acc[m][n] = (f32x4)(0.f);

  for (int ks = 0; ks < DH / 32; ++ks) {
    gl_lds16(pa0, lA0); gl_lds16(pa1, lA1);
    gl_lds16(pb0, lB0); gl_lds16(pb1, lB1);
    pa0 += 32; pa1 += 32; pb0 += 32; pb1 += 32;
    __syncthreads();
    bf16x8 af[4], bfv[4];
#pragma unroll
    for (int m = 0; m < 4; ++m) af[m] = *(const bf16x8*)&As[fq][wr + m * 16 + fr][0];
#pragma unroll
    for (int n = 0; n < 4; ++n) bfv[n] = *(const bf16x8*)&Bs[fq][wc + n * 16 + fr][0];
#pragma unroll
    for (int m = 0; m < 4; ++m)
#pragma unroll
      for (int n = 0; n < 4; ++n)
        acc[m][n] = __builtin_amdgcn_mfma_f32_16x16x32_bf16(af[m], bfv[n], acc[m][n], 0, 0, 0);
    __syncthreads();
  }

  int tok[4][4]; float gv4[4][4];
#pragma unroll
  for (int m = 0; m < 4; ++m) {
    const int rb = row0 + wr + m * 16 + fq * 4;
#pragma unroll
    for (int i = 0; i < 4; ++i) {
      const int t = tlist[rb + i];
      tok[m][i] = t;
      gv4[m][i] = (t >= 0) ? gval[t] : 0.f;
    }
  }
#pragma unroll
  for (int n = 0; n < 4; ++n) {
    const int d = d0 + wc + n * 16 + fr;
    const float bias = b2[(size_t)e * DD + d];
#pragma unroll
    for (int m = 0; m < 4; ++m)
#pragma unroll
      for (int i = 0; i < 4; ++i) {
        const int t = tok[m][i];
        if (t >= 0) out[(size_t)t * DD + d] = (acc[m][n][i] + bias) * gv4[m][i];
      }
  }
}

extern "C" void kernel_launch(void* const* d_in, const int* in_sizes, int n_in,
                              void* d_out, int out_size, void* d_ws, size_t ws_size,
                              hipStream_t stream) {
  const float* x  = (const float*)d_in[0];
  const float* Wr = (const float*)d_in[1];
  const float* br = (const float*)d_in[2];
  const float* W1 = (const float*)d_in[3];
  const float* b1 = (const float*)d_in[4];
  const float* W2 = (const float*)d_in[5];
  const float* b2 = (const float*)d_in[6];
  float* out = (float*)d_out;

  char* ws = (char*)d_ws;
  int*   counts = (int*)ws;                       // 256 B
  int*   offs   = (int*)(ws + 256);               // 256 B
  float* gval   = (float*)(ws + 512);             // 32 KB
  int*   gidx   = (int*)(ws + 512 + 32768);       // 32 KB
  int*   gpos   = (int*)(ws + 512 + 65536);       // 32 KB
  int*   tlist  = (int*)(ws + 512 + 98304);       // SLOTS*4 = 34816 B
  size_t off = 512 + 98304 + 34816;               // 133632, 256B aligned
  u16* xb  = (u16*)(ws + off); off += (size_t)DN * DD * 2;        // 16 MB
  u16* w1t = (u16*)(ws + off); off += (size_t)DE * DH * DD * 2;   // 32 MB
  u16* w2t = (u16*)(ws + off); off += (size_t)DE * DD * DH * 2;   // 32 MB
  u16* hb  = (u16*)(ws + off);                                    // SLOTS*DH*2 = 68 MB

  hipMemsetAsync(counts, 0, 256, stream);
  hipMemsetAsync(tlist, 0xFF, SLOTS * sizeof(int), stream);

  router_k<<<dim3(DN / 4), 256, 0, stream>>>(x, Wr, br, gval, gidx, gpos, counts, xb);
  offsets_k<<<dim3(1), 64, 0, stream>>>(counts, offs);
  scatter_k<<<dim3(DN / 256), 256, 0, stream>>>(gidx, gpos, offs, tlist);
  transpose_conv<<<dim3(DD / 64, DH / 64, DE), 256, 0, stream>>>(W1, w1t, DD, DH);
  transpose_conv<<<dim3(DH / 64, DD / 64, DE), 256, 0, stream>>>(W2, w2t, DH, DD);
  gemm1_k<<<dim3(DN / 128 + DE, DH / 128), 256, 0, stream>>>(xb, w1t, b1, tlist, offs, hb);
  gemm2_k<<<dim3(DN / 128 + DE, DD / 128), 256, 0, stream>>>(hb, w2t, b2, tlist, offs, gval, out);
}

// Round 3
// 677.875 us; speedup vs baseline: 1.0528x; 1.0528x over previous
//
#include <hip/hip_runtime.h>

// Problem: B=4,S=2048 -> N=8192 tokens, D=1024, H=4096, E=4 experts, top-1 routing.
#define DN 8192
#define DD 1024
#define DH 4096
#define DE 4
#define SLOTS (DN + 512)   // padded concat token list (each expert segment 128-aligned)

typedef unsigned short u16;
typedef float f32x4 __attribute__((ext_vector_type(4)));
typedef __bf16 bf16x8 __attribute__((ext_vector_type(8)));
typedef u16 u16x2 __attribute__((ext_vector_type(2)));
typedef u16 u16x4 __attribute__((ext_vector_type(4)));

__device__ __forceinline__ u16 f2b(float f) {
  union { float f; unsigned u; } v; v.f = f;
  return (u16)((v.u + 0x7FFFu + ((v.u >> 16) & 1u)) >> 16);  // RNE f32->bf16
}

__device__ __forceinline__ void gl_lds16(const u16* g, u16* l) {
  __builtin_amdgcn_global_load_lds((const __attribute__((address_space(1))) void*)g,
                                   (__attribute__((address_space(3))) void*)l, 16, 0, 0);
}

// ---------------- router: 1 wave per token, fp64 accumulation for argmax safety ----------
__global__ __launch_bounds__(256) void router_k(const float* __restrict__ x,
    const float* __restrict__ Wr, const float* __restrict__ br,
    float* __restrict__ gval, int* __restrict__ gidx, int* __restrict__ gpos,
    int* __restrict__ counts, u16* __restrict__ xb)
{
  const int tid = blockIdx.x * 256 + threadIdx.x;
  const int n = tid >> 6, lane = tid & 63;
  const float* xr = x + (size_t)n * DD;
  double a0 = 0., a1 = 0., a2 = 0., a3 = 0.;
#pragma unroll
  for (int k = 0; k < DD / 64; ++k) {
    const int d = lane + k * 64;
    const float xv = xr[d];
    const f32x4 w = *(const f32x4*)&Wr[d * 4];
    a0 += (double)xv * w[0]; a1 += (double)xv * w[1];
    a2 += (double)xv * w[2]; a3 += (double)xv * w[3];
    xb[(size_t)n * DD + d] = f2b(xv);
  }
#pragma unroll
  for (int off = 32; off; off >>= 1) {
    a0 += __shfl_xor(a0, off);
    a1 += __shfl_xor(a1, off);
    a2 += __shfl_xor(a2, off);
    a3 += __shfl_xor(a3, off);
  }
  if (lane == 0) {
    const double l0 = a0 + br[0], l1 = a1 + br[1], l2 = a2 + br[2], l3 = a3 + br[3];
    int bi = 0; double bm = l0;
    if (l1 > bm) { bm = l1; bi = 1; }
    if (l2 > bm) { bm = l2; bi = 2; }
    if (l3 > bm) { bm = l3; bi = 3; }
    const float s = __expf((float)(l0 - bm)) + __expf((float)(l1 - bm)) +
                    __expf((float)(l2 - bm)) + __expf((float)(l3 - bm));
    gval[n] = 1.0f / s;          // max softmax prob
    gidx[n] = bi;
    gpos[n] = atomicAdd(&counts[bi], 1);
  }
}

__global__ void offsets_k(const int* __restrict__ counts, int* __restrict__ offs) {
  if (threadIdx.x == 0 && blockIdx.x == 0) {
    int o = 0;
#pragma unroll
    for (int e = 0; e < DE; ++e) { offs[e] = o; o += (counts[e] + 127) & ~127; }
    offs[DE] = o;
  }
}

__global__ __launch_bounds__(256) void scatter_k(const int* __restrict__ gidx,
    const int* __restrict__ gpos, const int* __restrict__ offs, int* __restrict__ tlist) {
  const int n = blockIdx.x * 256 + threadIdx.x;
  tlist[offs[gidx[n]] + gpos[n]] = n;
}

// ---------------- fp32 -> bf16 transpose (in: R x C, out: C x R), per blockIdx.z matrix ----
__global__ __launch_bounds__(256) void transpose_conv(const float* __restrict__ in,
    u16* __restrict__ out, int R, int C)
{
  __shared__ u16 t[64][66];
  const int r0 = blockIdx.x * 64, c0 = blockIdx.y * 64;
  const size_t mo = (size_t)blockIdx.z * R * C;
  const int tid = threadIdx.x;
  const int i = tid >> 4, j0 = (tid & 15) * 4;
#pragma unroll
  for (int k = 0; k < 4; ++k) {
    const int row = k * 16 + i;
    const f32x4 v = *(const f32x4*)&in[mo + (size_t)(r0 + row) * C + c0 + j0];
    u16x2 u01; u01[0] = f2b(v[0]); u01[1] = f2b(v[1]);
    u16x2 u23; u23[0] = f2b(v[2]); u23[1] = f2b(v[3]);
    *(u16x2*)&t[row][j0] = u01;
    *(u16x2*)&t[row][j0 + 2] = u23;
  }
  __syncthreads();
#pragma unroll
  for (int k = 0; k < 4; ++k) {
    const int p = k * 16 + i;   // out-row within tile
    u16x4 u;
    u[0] = t[j0 + 0][p]; u[1] = t[j0 + 1][p]; u[2] = t[j0 + 2][p]; u[3] = t[j0 + 3][p];
    *(u16x4*)&out[mo + (size_t)(c0 + p) * R + r0 + j0] = u;
  }
}

// ---- shared 2-phase GEMM machinery (128x128 tile, 4 waves, BK=32, double-buffered LDS) ----
// Per-iter: issue prefetch of tile ks+1 into buf NXT, wait counted vmcnt(4) so buf CUR's
// 4 older loads are complete (prefetch stays in flight), barrier, ds_read+MFMA from CUR,
// barrier. Readers of CUR finish (lgkmcnt before MFMA) before barrier 2, which precedes
// the overwrite of CUR (staged one full iteration later) -> race-free.
#define STAGE(ks, B) do { \
    gl_lds16(pa0 + (size_t)(ks) * 32, &As[B][wid][0][0]); \
    gl_lds16(pa1 + (size_t)(ks) * 32, &As[B][wid][64][0]); \
    gl_lds16(pb0 + (size_t)(ks) * 32, &Bs[B][wid][0][0]); \
    gl_lds16(pb1 + (size_t)(ks) * 32, &Bs[B][wid][64][0]); \
  } while (0)

#define COMPUTE(B) do { \
    bf16x8 af[4], bfv[4]; \
    _Pragma("unroll") \
    for (int m = 0; m < 4; ++m) af[m] = *(const bf16x8*)&As[B][fq][wr + m * 16 + fr][0]; \
    _Pragma("unroll") \
    for (int n = 0; n < 4; ++n) bfv[n] = *(const bf16x8*)&Bs[B][fq][wc + n * 16 + fr][0]; \
    _Pragma("unroll") \
    for (int m = 0; m < 4; ++m) \
      _Pragma("unroll") \
      for (int n = 0; n < 4; ++n) \
        acc[m][n] = __builtin_amdgcn_mfma_f32_16x16x32_bf16(af[m], bfv[n], acc[m][n], 0, 0, 0); \
  } while (0)

#define GITER(ks, CUR, NXT, NK) do { \
    if ((ks) + 1 < (NK)) { \
      STAGE((ks) + 1, NXT); \
      asm volatile("s_waitcnt vmcnt(4)" ::: "memory"); \
    } else { \
      asm volatile("s_waitcnt vmcnt(0)" ::: "memory"); \
    } \
    __builtin_amdgcn_s_barrier(); \
    __builtin_amdgcn_sched_barrier(0); \
    COMPUTE(CUR); \
    __builtin_amdgcn_sched_barrier(0); \
    __builtin_amdgcn_s_barrier(); \
  } while (0)

// ---------------- grouped GEMM1: Hb[slot,h] = silu(x[tok] @ W1[e] + b1[e]) ----------------
__global__ __launch_bounds__(256) void gemm1_k(const u16* __restrict__ xb,
    const u16* __restrict__ w1t, const float* __restrict__ b1,
    const int* __restrict__ tlist, const int* __restrict__ offs, u16* __restrict__ hb)
{
  __shared__ u16 As[2][4][128][8];   // [dbuf][kchunk][row][8 bf16]
  __shared__ u16 Bs[2][4][128][8];
  const int row0 = blockIdx.x * 128;
  if (row0 >= offs[DE]) return;
  int e = 0;
  if (row0 >= offs[1]) e = 1;
  if (row0 >= offs[2]) e = 2;
  if (row0 >= offs[3]) e = 3;
  const int h0 = blockIdx.y * 128;
  const int tid = threadIdx.x;
  const int wid = tid >> 6, lane = tid & 63;

  int tA0 = tlist[row0 + lane];
  int tA1 = tlist[row0 + 64 + lane];
  if (tA0 < 0) tA0 = 0;
  if (tA1 < 0) tA1 = 0;
  const u16* pa0 = xb + (size_t)tA0 * DD + wid * 8;
  const u16* pa1 = xb + (size_t)tA1 * DD + wid * 8;
  const u16* pb0 = w1t + (size_t)e * DH * DD + (size_t)(h0 + lane) * DD + wid * 8;
  const u16* pb1 = w1t + (size_t)e * DH * DD + (size_t)(h0 + 64 + lane) * DD + wid * 8;

  const int wr = (wid >> 1) * 64, wc = (wid & 1) * 64;
  const int fr = lane & 15, fq = lane >> 4;

  f32x4 acc[4][4];
#pragma unroll
  for (int m = 0; m < 4; ++m)
#pragma unroll
    for (int n = 0; n < 4; ++n) acc[m][n] = (f32x4)(0.f);

  STAGE(0, 0);
#pragma unroll 1
  for (int ks = 0; ks < DD / 32; ks += 2) {
    GITER(ks, 0, 1, DD / 32);
    GITER(ks + 1, 1, 0, DD / 32);
  }

#pragma unroll
  for (int n = 0; n < 4; ++n) {
    const int h = h0 + wc + n * 16 + fr;
    const float bias = b1[(size_t)e * DH + h];
#pragma unroll
    for (int m = 0; m < 4; ++m) {
      const int r = row0 + wr + m * 16 + fq * 4;
      const f32x4 v = acc[m][n];
#pragma unroll
      for (int i = 0; i < 4; ++i) {
        const float xv = v[i] + bias;
        const float sv = xv / (1.f + __expf(-xv));   // silu
        hb[(size_t)(r + i) * DH + h] = f2b(sv);
      }
    }
  }
}

// ---- grouped GEMM2 (split-K=2): psum_z[tok,d] = Hb[slot, z*2048 : (z+1)*2048] @ W2[e] ----
__global__ __launch_bounds__(256) void gemm2_k(const u16* __restrict__ hb,
    const u16* __restrict__ w2t, const int* __restrict__ tlist,
    const int* __restrict__ offs, float* __restrict__ out, float* __restrict__ p1)
{
  __shared__ u16 As[2][4][128][8];
  __shared__ u16 Bs[2][4][128][8];
  const int row0 = blockIdx.x * 128;
  if (row0 >= offs[DE]) return;
  int e = 0;
  if (row0 >= offs[1]) e = 1;
  if (row0 >= offs[2]) e = 2;
  if (row0 >= offs[3]) e = 3;
  const int d0 = blockIdx.y * 128;
  const int kb = blockIdx.z * (DH / 2);   // K-slice base
  const int tid = threadIdx.x;
  const int wid = tid >> 6, lane = tid & 63;

  const u16* pa0 = hb + (size_t)(row0 + lane) * DH + kb + wid * 8;
  const u16* pa1 = hb + (size_t)(row0 + 64 + lane) * DH + kb + wid * 8;
  const u16* pb0 = w2t + (size_t)e * DD * DH + (size_t)(d0 + lane) * DH + kb + wid * 8;
  const u16* pb1 = w2t + (size_t)e * DD * DH + (size_t)(d0 + 64 + lane) * DH + kb + wid * 8;

  const int wr = (wid >> 1) * 64, wc = (wid & 1) * 64;
  const int fr = lane & 15, fq = lane >> 4;

  f32x4 acc[4][4];
#pragma unroll
  for (int m = 0; m < 4; ++m)
#pragma unroll
    for (int n = 0; n < 4; ++n) acc[m][n] = (f32x4)(0.f);

  STAGE(0, 0);
#pragma unroll 1
  for (int ks = 0; ks < DH / 2 / 32; ks += 2) {
    GITER(ks, 0, 1, DH / 2 / 32);
    GITER(ks + 1, 1, 0, DH / 2 / 32);
  }

  float* __restrict__ dst = (blockIdx.z == 0) ? out : p1;
  int tok[4][4];
#pragma unroll
  for (int m = 0; m < 4; ++m) {
    const int rb = row0 + wr + m * 16 + fq * 4;
#pragma unroll
    for (int i = 0; i < 4; ++i) tok[m][i] = tlist[rb + i];
  }
#pragma unroll
  for (int n = 0; n < 4; ++n) {
    const int d = d0 + wc + n * 16 + fr;
#pragma unroll
    for (int m = 0; m < 4; ++m)
#pragma unroll
      for (int i = 0; i < 4; ++i) {
        const int t = tok[m][i];
        if (t >= 0) dst[(size_t)t * DD + d] = acc[m][n][i];
      }
  }
}

// ---------------- reduce: out = (p0 + p1 + b2[e]) * gate ----------------
__global__ __launch_bounds__(256) void reduce2_k(float* __restrict__ out,
    const float* __restrict__ p1, const float* __restrict__ b2,
    const int* __restrict__ gidx, const float* __restrict__ gval)
{
  const size_t idx = ((size_t)blockIdx.x * 256 + threadIdx.x) * 4;
  const int n = (int)(idx >> 10);       // / DD
  const int d = (int)(idx & (DD - 1));
  const int e = gidx[n];
  const float g = gval[n];
  f32x4 a = *(f32x4*)&out[idx];
  const f32x4 b = *(const f32x4*)&p1[idx];
  const f32x4 bb = *(const f32x4*)&b2[(size_t)e * DD + d];
  f32x4 r;
#pragma unroll
  for (int j = 0; j < 4; ++j) r[j] = (a[j] + b[j] + bb[j]) * g;
  *(f32x4*)&out[idx] = r;
}

extern "C" void kernel_launch(void* const* d_in, const int* in_sizes, int n_in,
                              void* d_out, int out_size, void* d_ws, size_t ws_size,
                              hipStream_t stream) {
  const float* x  = (const float*)d_in[0];
  const float* Wr = (const float*)d_in[1];
  const float* br = (const float*)d_in[2];
  const float* W1 = (const float*)d_in[3];
  const float* b1 = (const float*)d_in[4];
  const float* W2 = (const float*)d_in[5];
  const float* b2 = (const float*)d_in[6];
  float* out = (float*)d_out;

  char* ws = (char*)d_ws;
  int*   counts = (int*)ws;                       // 256 B
  int*   offs   = (int*)(ws + 256);               // 256 B
  float* gval   = (float*)(ws + 512);             // 32 KB
  int*   gidx   = (int*)(ws + 512 + 32768);       // 32 KB
  int*   gpos   = (int*)(ws + 512 + 65536);       // 32 KB
  int*   tlist  = (int*)(ws + 512 + 98304);       // SLOTS*4 = 34816 B
  size_t off = 512 + 98304 + 34816;               // 133632, 16B aligned
  u16* xb  = (u16*)(ws + off);
  float* p1 = (float*)(ws + off);                 // overlays xb+w1t (dead during gemm2)
  off += (size_t)DN * DD * 2;                     // 16 MB
  u16* w1t = (u16*)(ws + off); off += (size_t)DE * DH * DD * 2;   // 32 MB
  u16* w2t = (u16*)(ws + off); off += (size_t)DE * DD * DH * 2;   // 32 MB
  u16* hb  = (u16*)(ws + off);                                    // SLOTS*DH*2 = 68 MB

  hipMemsetAsync(counts, 0, 256, stream);
  hipMemsetAsync(tlist, 0xFF, SLOTS * sizeof(int), stream);

  router_k<<<dim3(DN / 4), 256, 0, stream>>>(x, Wr, br, gval, gidx, gpos, counts, xb);
  offsets_k<<<dim3(1), 64, 0, stream>>>(counts, offs);
  scatter_k<<<dim3(DN / 256), 256, 0, stream>>>(gidx, gpos, offs, tlist);
  transpose_conv<<<dim3(DD / 64, DH / 64, DE), 256, 0, stream>>>(W1, w1t, DD, DH);
  transpose_conv<<<dim3(DH / 64, DD / 64, DE), 256, 0, stream>>>(W2, w2t, DH, DD);
  gemm1_k<<<dim3(DN / 128 + DE, DH / 128), 256, 0, stream>>>(xb, w1t, b1, tlist, offs, hb);
  gemm2_k<<<dim3(DN / 128 + DE, DD / 128, 2), 256, 0, stream>>>(hb, w2t, tlist, offs, out, p1);
  reduce2_k<<<dim3(DN * DD / 4 / 256), 256, 0, stream>>>(out, p1, b2, gidx, gval);
}